// Round 8
// baseline (55.218 us; speedup 1.0000x reference)
//
#include <hip/hip_runtime.h>

constexpr int H = 192, W = 192, D = 192;
constexpr int BH = 8, BW = 8, BZ = 16;     // output tile per block per step
constexpr int TY = 16, TX = 16, TZ = 24;   // staged slab: halo -4..+11 (x,y), -4..+19 (z)
constexpr int TILE_N = TY * TX * TZ;       // 6144 dwords = 24 KB per buffer
constexpr int KSTEPS = 6;                  // z-steps per block
constexpr int ZSPAN = BZ * KSTEPS;         // 96

// Exact reference semantics for one voxel, all-global (fallback path).
__device__ __forceinline__ float ref_voxel(const float* __restrict__ I,
                                           float x, float y, float zf)
{
    int fx = (int)floorf(x), fy = (int)floorf(y), fz = (int)floorf(zf);
    int x0 = min(max(fx, 0), W + 1), x1 = min(max(fx + 1, 0), W + 1);
    int y0 = min(max(fy, 0), H + 1), y1 = min(max(fy + 1, 0), H + 1);
    int zp0 = min(max(fz, 0), D + 1), zp1 = min(max(fz + 1, 0), D + 1);
    float dx = (float)x1 - x, dy = (float)y1 - y, dz = (float)zp1 - zf;
    int xi0 = x0 - 1, xi1 = x1 - 1, yi0 = y0 - 1, yi1 = y1 - 1;
    int zi = zp0 - 1, zj = zp1 - 1;
    float ax0 = ((unsigned)xi0 < (unsigned)W) ? dx       : 0.f;
    float ax1 = ((unsigned)xi1 < (unsigned)W) ? 1.f - dx : 0.f;
    float ay0 = ((unsigned)yi0 < (unsigned)H) ? dy       : 0.f;
    float ay1 = ((unsigned)yi1 < (unsigned)H) ? 1.f - dy : 0.f;
    float az0 = ((unsigned)zi  < (unsigned)D) ? dz       : 0.f;
    float az1 = ((unsigned)zj  < (unsigned)D) ? 1.f - dz : 0.f;
    int xc0 = min(max(xi0, 0), W - 1), xc1 = min(max(xi1, 0), W - 1);
    int yc0 = min(max(yi0, 0), H - 1), yc1 = min(max(yi1, 0), H - 1);
    int zc0 = min(max(zi, 0), D - 1),  zc1 = min(max(zj, 0), D - 1);
    const float* r00 = I + (yc0 * W + xc0) * D;
    const float* r01 = I + (yc0 * W + xc1) * D;
    const float* r10 = I + (yc1 * W + xc0) * D;
    const float* r11 = I + (yc1 * W + xc1) * D;
    float s00 = az0 * r00[zc0] + az1 * r00[zc1];
    float s01 = az0 * r01[zc0] + az1 * r01[zc1];
    float s10 = az0 * r10[zc0] + az1 * r10[zc1];
    float s11 = az0 * r11[zc0] + az1 * r11[zc1];
    return ay0 * (ax0 * s00 + ax1 * s01) + ay1 * (ax0 * s10 + ax1 * s11);
}

// R7-verified slab staging: per-lane CLAMPED source, linear LDS dest.
__device__ __forceinline__ void stage_slab(const float* __restrict__ I,
                                           float* dst, int xg0, int yg0, int zg0,
                                           int tid)
{
    const unsigned wv = tid >> 6, lane = tid & 63;
    #pragma unroll
    for (unsigned t = 0; t < 6; ++t) {          // 24 wave-instructions total
        unsigned i = wv + t * 4u;
        unsigned c = i * 64u + lane;
        unsigned rowc = c / 6u;
        unsigned s = c - rowc * 6u;
        unsigned ry = rowc >> 4, rx = rowc & 15u;
        int gy = min(max(yg0 + (int)ry, 0), H - 1);
        int gx = min(max(xg0 + (int)rx, 0), W - 1);
        int zs = min(max(zg0 + (int)(s * 4u), 0), D - 4);
        const float* src = I + ((gy * W + gx) * D + zs);
        __builtin_amdgcn_global_load_lds(
            (const __attribute__((address_space(1))) void*)src,
            (__attribute__((address_space(3))) void*)(dst + i * 256u),
            16, 0, 0);
    }
}

__global__ __launch_bounds__(256, 3) void st_march(
    const float* __restrict__ I,
    const float* __restrict__ dxt,
    const float* __restrict__ dyt,
    const float* __restrict__ dzt,
    float* __restrict__ out)
{
    __shared__ __align__(16) float tile[2][TILE_N];   // 48 KB -> 3 blocks/CU

    const int tid = threadIdx.x;
    const int bx = blockIdx.x, by = blockIdx.y, bzc = blockIdx.z;
    const int w0 = bx * BW, h0 = by * BH, zb = bzc * ZSPAN;
    const int xg0 = w0 - 4, yg0 = h0 - 4;

    const int zq = tid & 3, wl = (tid >> 2) & 7, hl = tid >> 5;
    const int wg = w0 + wl, hg = h0 + hl;
    const int rowbase = (hg * W + wg) * (D / 4) + zq;   // + z0/4 per step

    // block-uniform fast-path bounds (x,y): tap fully interior AND inside slab
    const int lox = max(0, -xg0),        hix = min(TX - 2, 190 - xg0);
    const int loy = max(0, -yg0),        hiy = min(TY - 2, 190 - yg0);

    // ---- prologue: stage step 0, load step-0 displacements ----
    stage_slab(I, tile[0], xg0, yg0, zb - 4, tid);
    float4 cx = reinterpret_cast<const float4*>(dxt)[rowbase + (zb >> 2)];
    float4 cy = reinterpret_cast<const float4*>(dyt)[rowbase + (zb >> 2)];
    float4 cz = reinterpret_cast<const float4*>(dzt)[rowbase + (zb >> 2)];
    asm volatile("s_waitcnt vmcnt(0)" ::: "memory");
    __syncthreads();

    #pragma unroll
    for (int k = 0; k < KSTEPS; ++k) {
        const int z0 = zb + k * BZ;
        const int zg0 = z0 - 4;
        const float* tl = tile[k & 1];

        // ---- issue next step's staging + displacement loads (overlap compute) ----
        float4 nx, ny, nz;
        if (k + 1 < KSTEPS) {
            stage_slab(I, tile[(k + 1) & 1], xg0, yg0, z0 + BZ - 4, tid);
            const int t4n = rowbase + ((z0 + BZ) >> 2);
            nx = reinterpret_cast<const float4*>(dxt)[t4n];
            ny = reinterpret_cast<const float4*>(dyt)[t4n];
            nz = reinterpret_cast<const float4*>(dzt)[t4n];
        }

        const int lozk = max(0, -zg0), hizk = min(TZ - 2, 190 - zg0);

        float rxj[4] = {cx.x, cx.y, cx.z, cx.w};
        float ryj[4] = {cy.x, cy.y, cy.z, cy.w};
        float rzj[4] = {cz.x, cz.y, cz.z, cz.w};
        float ro[4];

        // ---- phase A: local coords + fast flags (fully unrolled, static idx) ----
        int   lxa[4], lya[4], lza[4];
        float txa[4], tya[4], tza[4];
        bool  fa[4];
        #pragma unroll
        for (int j = 0; j < 4; ++j) {
            float xl = rxj[j] + (float)(wl + 4);
            float yl = ryj[j] + (float)(hl + 4);
            float zl = rzj[j] + (float)(zq * 4 + j + 4);
            float fxf = floorf(xl), fyf = floorf(yl), fzf = floorf(zl);
            lxa[j] = (int)fxf; lya[j] = (int)fyf; lza[j] = (int)fzf;
            txa[j] = xl - fxf; tya[j] = yl - fyf; tza[j] = zl - fzf;
            fa[j] = ((unsigned)(lxa[j] - lox) <= (unsigned)(hix - lox))
                  & ((unsigned)(lya[j] - loy) <= (unsigned)(hiy - loy))
                  & ((unsigned)(lza[j] - lozk) <= (unsigned)(hizk - lozk));
        }

        if (__builtin_expect(__all(fa[0] & fa[1] & fa[2] & fa[3]), 1)) {
            // ---- fast path: no clamps, plain frac weights (R4-verified) ----
            #pragma unroll
            for (int j = 0; j < 4; ++j) {
                int b = (lya[j] * TX + lxa[j]) * TZ + lza[j];
                float a0 = tl[b],               a1 = tl[b + 1];
                float b0 = tl[b + TZ],          b1 = tl[b + TZ + 1];
                float c0 = tl[b + TX * TZ],     c1 = tl[b + TX * TZ + 1];
                float d0 = tl[b + TX * TZ + TZ], d1 = tl[b + TX * TZ + TZ + 1];
                float wz0 = 1.f - tza[j], wz1 = tza[j];
                float wx0 = 1.f - txa[j], wx1 = txa[j];
                float wy0 = 1.f - tya[j], wy1 = tya[j];
                float s00 = wz0 * a0 + wz1 * a1;
                float s01 = wz0 * b0 + wz1 * b1;
                float s10 = wz0 * c0 + wz1 * c1;
                float s11 = wz0 * d0 + wz1 * d1;
                ro[j] = wy0 * (wx0 * s00 + wx1 * s01) + wy1 * (wx0 * s10 + wx1 * s11);
            }
        } else {
            // ---- full path: reference clamp semantics (R6/R7-verified) ----
            #pragma unroll
            for (int j = 0; j < 4; ++j) {
                const int zv = z0 + zq * 4 + j;
                float x  = rxj[j] + (float)(wg + 1);
                float y  = ryj[j] + (float)(hg + 1);
                float zf = rzj[j] + (float)(zv + 1);

                int fx = (int)floorf(x), fy = (int)floorf(y), fz = (int)floorf(zf);
                int x0 = min(max(fx, 0), W + 1), x1 = min(max(fx + 1, 0), W + 1);
                int y0 = min(max(fy, 0), H + 1), y1 = min(max(fy + 1, 0), H + 1);
                int zp0 = min(max(fz, 0), D + 1), zp1 = min(max(fz + 1, 0), D + 1);

                float dx = (float)x1 - x, dy = (float)y1 - y, dz = (float)zp1 - zf;

                int xi0 = x0 - 1, xi1 = x1 - 1, yi0 = y0 - 1, yi1 = y1 - 1;
                int zi = zp0 - 1, zj2 = zp1 - 1;

                float ax0 = ((unsigned)xi0 < (unsigned)W) ? dx       : 0.f;
                float ax1 = ((unsigned)xi1 < (unsigned)W) ? 1.f - dx : 0.f;
                float ay0 = ((unsigned)yi0 < (unsigned)H) ? dy       : 0.f;
                float ay1 = ((unsigned)yi1 < (unsigned)H) ? 1.f - dy : 0.f;
                float az0 = ((unsigned)zi  < (unsigned)D) ? dz       : 0.f;
                float az1 = ((unsigned)zj2 < (unsigned)D) ? 1.f - dz : 0.f;

                int xc0 = min(max(xi0, 0), W - 1), xc1 = min(max(xi1, 0), W - 1);
                int yc0 = min(max(yi0, 0), H - 1), yc1 = min(max(yi1, 0), H - 1);
                int zc  = min(max(zi, 0), D - 2);

                bool zlo = (zi <= D - 2);
                bool zhi = (zi >= 0);

                int lx0 = xc0 - xg0, lx1 = xc1 - xg0;
                int ly0 = yc0 - yg0, ly1 = yc1 - yg0;
                int lz  = zc - zg0;

                bool ok = ((unsigned)lx0 <= (unsigned)(TX - 1))
                        & ((unsigned)lx1 <= (unsigned)(TX - 1))
                        & ((unsigned)ly0 <= (unsigned)(TY - 1))
                        & ((unsigned)ly1 <= (unsigned)(TY - 1))
                        & ((unsigned)lz  <= (unsigned)(TZ - 2));

                int b00 = min(max((ly0 * TX + lx0) * TZ + lz, 0), TILE_N - 2);
                int b01 = min(max((ly0 * TX + lx1) * TZ + lz, 0), TILE_N - 2);
                int b10 = min(max((ly1 * TX + lx0) * TZ + lz, 0), TILE_N - 2);
                int b11 = min(max((ly1 * TX + lx1) * TZ + lz, 0), TILE_N - 2);

                float a0 = tl[b00], a1 = tl[b00 + 1];
                float b0 = tl[b01], b1 = tl[b01 + 1];
                float c0 = tl[b10], c1 = tl[b10 + 1];
                float d0 = tl[b11], d1 = tl[b11 + 1];

                float v000 = zlo ? a0 : a1, v001 = zhi ? a1 : a0;
                float v010 = zlo ? b0 : b1, v011 = zhi ? b1 : b0;
                float v100 = zlo ? c0 : c1, v101 = zhi ? c1 : c0;
                float v110 = zlo ? d0 : d1, v111 = zhi ? d1 : d0;
                float s00 = az0 * v000 + az1 * v001;
                float s01 = az0 * v010 + az1 * v011;
                float s10 = az0 * v100 + az1 * v101;
                float s11 = az0 * v110 + az1 * v111;
                float r = ay0 * (ax0 * s00 + ax1 * s01)
                        + ay1 * (ax0 * s10 + ax1 * s11);

                ro[j] = __builtin_expect(ok, 1) ? r : ref_voxel(I, x, y, zf);
            }
        }

        reinterpret_cast<float4*>(out)[rowbase + (z0 >> 2)] =
            make_float4(ro[0], ro[1], ro[2], ro[3]);

        // drain next-step staging (in flight during compute) + sync buffers
        asm volatile("s_waitcnt vmcnt(0)" ::: "memory");
        __syncthreads();

        if (k + 1 < KSTEPS) { cx = nx; cy = ny; cz = nz; }
    }
}

extern "C" void kernel_launch(void* const* d_in, const int* in_sizes, int n_in,
                              void* d_out, int out_size, void* d_ws, size_t ws_size,
                              hipStream_t stream) {
    const float* I   = (const float*)d_in[0];
    const float* dxt = (const float*)d_in[1];
    const float* dyt = (const float*)d_in[2];
    const float* dzt = (const float*)d_in[3];
    float* out = (float*)d_out;

    dim3 grid(W / BW, H / BH, D / ZSPAN);   // 24 x 24 x 2
    hipLaunchKernelGGL(st_march, grid, dim3(256), 0, stream,
                       I, dxt, dyt, dzt, out);
}

// Round 9
// 49.292 us; speedup vs baseline: 1.1202x; 1.1202x over previous
//
#include <hip/hip_runtime.h>

constexpr int H = 192, W = 192, D = 192;
constexpr int BH = 8, BW = 8, BZ = 16;     // output tile per block per step
constexpr int TY = 16, TX = 16, TZ = 24;   // staged slab: halo -4..+11 (x,y), -4..+19 (z)
constexpr int TILE_N = TY * TX * TZ;       // 6144 dwords = 24 KB per buffer
constexpr int KSTEPS = 3;                  // z-steps per block
constexpr int ZSPAN = BZ * KSTEPS;         // 48

// Exact reference semantics for one voxel, all-global (fallback path).
__device__ __forceinline__ float ref_voxel(const float* __restrict__ I,
                                           float x, float y, float zf)
{
    int fx = (int)floorf(x), fy = (int)floorf(y), fz = (int)floorf(zf);
    int x0 = min(max(fx, 0), W + 1), x1 = min(max(fx + 1, 0), W + 1);
    int y0 = min(max(fy, 0), H + 1), y1 = min(max(fy + 1, 0), H + 1);
    int zp0 = min(max(fz, 0), D + 1), zp1 = min(max(fz + 1, 0), D + 1);
    float dx = (float)x1 - x, dy = (float)y1 - y, dz = (float)zp1 - zf;
    int xi0 = x0 - 1, xi1 = x1 - 1, yi0 = y0 - 1, yi1 = y1 - 1;
    int zi = zp0 - 1, zj = zp1 - 1;
    float ax0 = ((unsigned)xi0 < (unsigned)W) ? dx       : 0.f;
    float ax1 = ((unsigned)xi1 < (unsigned)W) ? 1.f - dx : 0.f;
    float ay0 = ((unsigned)yi0 < (unsigned)H) ? dy       : 0.f;
    float ay1 = ((unsigned)yi1 < (unsigned)H) ? 1.f - dy : 0.f;
    float az0 = ((unsigned)zi  < (unsigned)D) ? dz       : 0.f;
    float az1 = ((unsigned)zj  < (unsigned)D) ? 1.f - dz : 0.f;
    int xc0 = min(max(xi0, 0), W - 1), xc1 = min(max(xi1, 0), W - 1);
    int yc0 = min(max(yi0, 0), H - 1), yc1 = min(max(yi1, 0), H - 1);
    int zc0 = min(max(zi, 0), D - 1),  zc1 = min(max(zj, 0), D - 1);
    const float* r00 = I + (yc0 * W + xc0) * D;
    const float* r01 = I + (yc0 * W + xc1) * D;
    const float* r10 = I + (yc1 * W + xc0) * D;
    const float* r11 = I + (yc1 * W + xc1) * D;
    float s00 = az0 * r00[zc0] + az1 * r00[zc1];
    float s01 = az0 * r01[zc0] + az1 * r01[zc1];
    float s10 = az0 * r10[zc0] + az1 * r10[zc1];
    float s11 = az0 * r11[zc0] + az1 * r11[zc1];
    return ay0 * (ax0 * s00 + ax1 * s01) + ay1 * (ax0 * s10 + ax1 * s11);
}

// R7/R8-verified slab staging: per-lane CLAMPED source, linear LDS dest.
// Per wave: exactly 6 global_load_lds (16B) instructions.
__device__ __forceinline__ void stage_slab(const float* __restrict__ I,
                                           float* dst, int xg0, int yg0, int zg0,
                                           int tid)
{
    const unsigned wv = tid >> 6, lane = tid & 63;
    #pragma unroll
    for (unsigned t = 0; t < 6; ++t) {          // 24 wave-instructions total
        unsigned i = wv + t * 4u;
        unsigned c = i * 64u + lane;
        unsigned rowc = c / 6u;
        unsigned s = c - rowc * 6u;
        unsigned ry = rowc >> 4, rx = rowc & 15u;
        int gy = min(max(yg0 + (int)ry, 0), H - 1);
        int gx = min(max(xg0 + (int)rx, 0), W - 1);
        int zs = min(max(zg0 + (int)(s * 4u), 0), D - 4);
        const float* src = I + ((gy * W + gx) * D + zs);
        __builtin_amdgcn_global_load_lds(
            (const __attribute__((address_space(1))) void*)src,
            (__attribute__((address_space(3))) void*)(dst + i * 256u),
            16, 0, 0);
    }
}

__global__ __launch_bounds__(256, 3) void st_march(
    const float* __restrict__ I,
    const float* __restrict__ dxt,
    const float* __restrict__ dyt,
    const float* __restrict__ dzt,
    float* __restrict__ out)
{
    __shared__ __align__(16) float tile[2][TILE_N];   // 48 KB -> 3 blocks/CU

    const int tid = threadIdx.x;
    const int bx = blockIdx.x, by = blockIdx.y, bzc = blockIdx.z;
    const int w0 = bx * BW, h0 = by * BH, zb = bzc * ZSPAN;
    const int xg0 = w0 - 4, yg0 = h0 - 4;

    const int zq = tid & 3, wl = (tid >> 2) & 7, hl = tid >> 5;
    const int wg = w0 + wl, hg = h0 + hl;
    const int rowbase = (hg * W + wg) * (D / 4) + zq;   // + z0/4 per step

    // block-uniform fast-path bounds (x,y) [R8-verified]
    const int lox = max(0, -xg0), hix = min(TX - 2, 190 - xg0);
    const int loy = max(0, -yg0), hiy = min(TY - 2, 190 - yg0);

    // ---- prologue: stage slab 0 + disp 0 (9 VMEM/wave, left in flight) ----
    stage_slab(I, tile[0], xg0, yg0, zb - 4, tid);
    float4 cx = reinterpret_cast<const float4*>(dxt)[rowbase + (zb >> 2)];
    float4 cy = reinterpret_cast<const float4*>(dyt)[rowbase + (zb >> 2)];
    float4 cz = reinterpret_cast<const float4*>(dzt)[rowbase + (zb >> 2)];

    #pragma unroll
    for (int k = 0; k < KSTEPS; ++k) {
        const int z0 = zb + k * BZ;
        const int zg0 = z0 - 4;
        const float* tl = tile[k & 1];

        // ---- issue next step's staging + disp loads (9 VMEM/wave) ----
        float4 nx, ny, nz;
        if (k + 1 < KSTEPS) {
            stage_slab(I, tile[(k + 1) & 1], xg0, yg0, z0 + BZ - 4, tid);
            const int t4n = rowbase + ((z0 + BZ) >> 2);
            nx = reinterpret_cast<const float4*>(dxt)[t4n];
            ny = reinterpret_cast<const float4*>(dyt)[t4n];
            nz = reinterpret_cast<const float4*>(dzt)[t4n];
        }

        // ---- counted wait: slab k + disp k done; slab k+1 stays in flight ----
        // in-order vmcnt: allow the 9 newest (S(k+1)+L(k+1)); force older done.
        if (k + 1 < KSTEPS) {
            asm volatile("s_waitcnt vmcnt(9)" ::: "memory");
        } else {
            asm volatile("s_waitcnt vmcnt(1)" ::: "memory");  // only prev store may remain
        }
        __builtin_amdgcn_s_barrier();            // raw barrier: no compiler vmcnt(0) drain
        __builtin_amdgcn_sched_barrier(0);

        const int lozk = max(0, -zg0), hizk = min(TZ - 2, 190 - zg0);

        float rxj[4] = {cx.x, cx.y, cx.z, cx.w};
        float ryj[4] = {cy.x, cy.y, cy.z, cy.w};
        float rzj[4] = {cz.x, cz.y, cz.z, cz.w};
        float ro[4];

        // ---- phase A: local coords + fast flags ----
        int   lxa[4], lya[4], lza[4];
        float txa[4], tya[4], tza[4];
        bool  fa[4];
        #pragma unroll
        for (int j = 0; j < 4; ++j) {
            float xl = rxj[j] + (float)(wl + 4);
            float yl = ryj[j] + (float)(hl + 4);
            float zl = rzj[j] + (float)(zq * 4 + j + 4);
            float fxf = floorf(xl), fyf = floorf(yl), fzf = floorf(zl);
            lxa[j] = (int)fxf; lya[j] = (int)fyf; lza[j] = (int)fzf;
            txa[j] = xl - fxf; tya[j] = yl - fyf; tza[j] = zl - fzf;
            fa[j] = ((unsigned)(lxa[j] - lox) <= (unsigned)(hix - lox))
                  & ((unsigned)(lya[j] - loy) <= (unsigned)(hiy - loy))
                  & ((unsigned)(lza[j] - lozk) <= (unsigned)(hizk - lozk));
        }

        if (__builtin_expect(__all(fa[0] & fa[1] & fa[2] & fa[3]), 1)) {
            // ---- fast path: no clamps, plain frac weights (R8-verified) ----
            #pragma unroll
            for (int j = 0; j < 4; ++j) {
                int b = (lya[j] * TX + lxa[j]) * TZ + lza[j];
                float a0 = tl[b],                a1 = tl[b + 1];
                float b0 = tl[b + TZ],           b1 = tl[b + TZ + 1];
                float c0 = tl[b + TX * TZ],      c1 = tl[b + TX * TZ + 1];
                float d0 = tl[b + TX * TZ + TZ], d1 = tl[b + TX * TZ + TZ + 1];
                float wz0 = 1.f - tza[j], wz1 = tza[j];
                float wx0 = 1.f - txa[j], wx1 = txa[j];
                float wy0 = 1.f - tya[j], wy1 = tya[j];
                float s00 = wz0 * a0 + wz1 * a1;
                float s01 = wz0 * b0 + wz1 * b1;
                float s10 = wz0 * c0 + wz1 * c1;
                float s11 = wz0 * d0 + wz1 * d1;
                ro[j] = wy0 * (wx0 * s00 + wx1 * s01) + wy1 * (wx0 * s10 + wx1 * s11);
            }
        } else {
            // ---- full path: reference clamp semantics (R6/R7/R8-verified) ----
            #pragma unroll
            for (int j = 0; j < 4; ++j) {
                const int zv = z0 + zq * 4 + j;
                float x  = rxj[j] + (float)(wg + 1);
                float y  = ryj[j] + (float)(hg + 1);
                float zf = rzj[j] + (float)(zv + 1);

                int fx = (int)floorf(x), fy = (int)floorf(y), fz = (int)floorf(zf);
                int x0 = min(max(fx, 0), W + 1), x1 = min(max(fx + 1, 0), W + 1);
                int y0 = min(max(fy, 0), H + 1), y1 = min(max(fy + 1, 0), H + 1);
                int zp0 = min(max(fz, 0), D + 1), zp1 = min(max(fz + 1, 0), D + 1);

                float dx = (float)x1 - x, dy = (float)y1 - y, dz = (float)zp1 - zf;

                int xi0 = x0 - 1, xi1 = x1 - 1, yi0 = y0 - 1, yi1 = y1 - 1;
                int zi = zp0 - 1, zj2 = zp1 - 1;

                float ax0 = ((unsigned)xi0 < (unsigned)W) ? dx       : 0.f;
                float ax1 = ((unsigned)xi1 < (unsigned)W) ? 1.f - dx : 0.f;
                float ay0 = ((unsigned)yi0 < (unsigned)H) ? dy       : 0.f;
                float ay1 = ((unsigned)yi1 < (unsigned)H) ? 1.f - dy : 0.f;
                float az0 = ((unsigned)zi  < (unsigned)D) ? dz       : 0.f;
                float az1 = ((unsigned)zj2 < (unsigned)D) ? 1.f - dz : 0.f;

                int xc0 = min(max(xi0, 0), W - 1), xc1 = min(max(xi1, 0), W - 1);
                int yc0 = min(max(yi0, 0), H - 1), yc1 = min(max(yi1, 0), H - 1);
                int zc  = min(max(zi, 0), D - 2);

                bool zlo = (zi <= D - 2);
                bool zhi = (zi >= 0);

                int lx0 = xc0 - xg0, lx1 = xc1 - xg0;
                int ly0 = yc0 - yg0, ly1 = yc1 - yg0;
                int lz  = zc - zg0;

                bool ok = ((unsigned)lx0 <= (unsigned)(TX - 1))
                        & ((unsigned)lx1 <= (unsigned)(TX - 1))
                        & ((unsigned)ly0 <= (unsigned)(TY - 1))
                        & ((unsigned)ly1 <= (unsigned)(TY - 1))
                        & ((unsigned)lz  <= (unsigned)(TZ - 2));

                int b00 = min(max((ly0 * TX + lx0) * TZ + lz, 0), TILE_N - 2);
                int b01 = min(max((ly0 * TX + lx1) * TZ + lz, 0), TILE_N - 2);
                int b10 = min(max((ly1 * TX + lx0) * TZ + lz, 0), TILE_N - 2);
                int b11 = min(max((ly1 * TX + lx1) * TZ + lz, 0), TILE_N - 2);

                float a0 = tl[b00], a1 = tl[b00 + 1];
                float b0 = tl[b01], b1 = tl[b01 + 1];
                float c0 = tl[b10], c1 = tl[b10 + 1];
                float d0 = tl[b11], d1 = tl[b11 + 1];

                float v000 = zlo ? a0 : a1, v001 = zhi ? a1 : a0;
                float v010 = zlo ? b0 : b1, v011 = zhi ? b1 : b0;
                float v100 = zlo ? c0 : c1, v101 = zhi ? c1 : c0;
                float v110 = zlo ? d0 : d1, v111 = zhi ? d1 : d0;
                float s00 = az0 * v000 + az1 * v001;
                float s01 = az0 * v010 + az1 * v011;
                float s10 = az0 * v100 + az1 * v101;
                float s11 = az0 * v110 + az1 * v111;
                float r = ay0 * (ax0 * s00 + ax1 * s01)
                        + ay1 * (ax0 * s10 + ax1 * s11);

                ro[j] = __builtin_expect(ok, 1) ? r : ref_voxel(I, x, y, zf);
            }
        }

        reinterpret_cast<float4*>(out)[rowbase + (z0 >> 2)] =
            make_float4(ro[0], ro[1], ro[2], ro[3]);

        // ---- buffer-swap barrier: compute-k reads done before k+2 staging ----
        __builtin_amdgcn_s_barrier();
        __builtin_amdgcn_sched_barrier(0);

        if (k + 1 < KSTEPS) { cx = nx; cy = ny; cz = nz; }
    }
}

extern "C" void kernel_launch(void* const* d_in, const int* in_sizes, int n_in,
                              void* d_out, int out_size, void* d_ws, size_t ws_size,
                              hipStream_t stream) {
    const float* I   = (const float*)d_in[0];
    const float* dxt = (const float*)d_in[1];
    const float* dyt = (const float*)d_in[2];
    const float* dzt = (const float*)d_in[3];
    float* out = (float*)d_out;

    dim3 grid(W / BW, H / BH, D / ZSPAN);   // 24 x 24 x 4 = 2304 blocks
    hipLaunchKernelGGL(st_march, grid, dim3(256), 0, stream,
                       I, dxt, dyt, dzt, out);
}